// Round 4
// baseline (56.344 us; speedup 1.0000x reference)
//
#include <hip/hip_runtime.h>
#include <math.h>

// LNCC, 3-kernel pipeline:
//  A: per 32x32 (h,w)-tile, loop over 8 d-slices with register double-buffer
//     prefetch (global->reg float4), W-pass sliding -> transposed LDS tmp ->
//     H-pass (b128 + sliding) -> u16 fixed-point intermediate (40 MB).
//  B: D-pass sliding window on u16 (exact in fp32) + LNCC + block reduce.
//  C: deterministic double reduction -> d_out[0] = -mean.

#define NVOX 4194304        // 2*128*128*128
#define SLICE 16384         // 128*128
#define QSCALE (65535.0f / 81.0f)
#define DQ ((float)(81.0 / 65535.0 / 729.0))

__device__ __forceinline__ int refl(int p) {
    // reflect (no edge repeat) for dim 128; valid for p in [-127, 254]
    return p < 0 ? -p : (p > 127 ? 254 - p : p);
}

__device__ __forceinline__ void load_slice(const float* __restrict__ fsl,
                                           const float* __restrict__ wsl,
                                           int rowoff, int jb,
                                           float fv[12], float wv[12]) {
    const float* frow = fsl + rowoff;
    const float* wrow = wsl + rowoff;
    if (jb >= 0 && jb <= 116) {          // reflect-free 12-word window
        *(float4*)&fv[0] = *(const float4*)&frow[jb];
        *(float4*)&fv[4] = *(const float4*)&frow[jb + 4];
        *(float4*)&fv[8] = *(const float4*)&frow[jb + 8];
        *(float4*)&wv[0] = *(const float4*)&wrow[jb];
        *(float4*)&wv[4] = *(const float4*)&wrow[jb + 4];
        *(float4*)&wv[8] = *(const float4*)&wrow[jb + 8];
    } else {
#pragma unroll
        for (int t = 0; t < 12; ++t) {
            int c = refl(jb + t);
            fv[t] = frow[c];
            wv[t] = wrow[c];
        }
    }
}

__device__ __forceinline__ void wh_compute_store(
        const float fv[12], const float wv[12],
        float (*tmpT)[32][44], int tid, int th0, int tw0, int slice,
        unsigned short* __restrict__ buf) {
    // Phase 1: W-pass. 320 tasks = (i 0..39) x (j-group 0..7, 4-wide).
    {
        const int i  = tid >> 3;
        const int j0 = (tid & 7) << 2;
        float sf = 0.f, sw = 0.f, sff = 0.f, sww = 0.f, sfw = 0.f;
#pragma unroll
        for (int t = 0; t < 9; ++t) {
            sf += fv[t]; sw += wv[t];
            sff = fmaf(fv[t], fv[t], sff);
            sww = fmaf(wv[t], wv[t], sww);
            sfw = fmaf(fv[t], wv[t], sfw);
        }
        tmpT[0][j0][i] = sf;  tmpT[1][j0][i] = sw;
        tmpT[2][j0][i] = sff; tmpT[3][j0][i] = sww; tmpT[4][j0][i] = sfw;
#pragma unroll
        for (int k = 1; k < 4; ++k) {
            float fe = fv[k + 8], fx = fv[k - 1];
            float we = wv[k + 8], wx = wv[k - 1];
            sf += fe - fx; sw += we - wx;
            sff = fmaf(fe, fe, sff); sff = fmaf(-fx, fx, sff);
            sww = fmaf(we, we, sww); sww = fmaf(-wx, wx, sww);
            sfw = fmaf(fe, we, sfw); sfw = fmaf(-fx, wx, sfw);
            tmpT[0][j0 + k][i] = sf;  tmpT[1][j0 + k][i] = sw;
            tmpT[2][j0 + k][i] = sff; tmpT[3][j0 + k][i] = sww;
            tmpT[4][j0 + k][i] = sfw;
        }
    }
    __syncthreads();

    // Phase 2: H-pass. 256 tasks = (j 0..31) x (i-group 0..7, 4-wide).
    if (tid < 256) {
        const int j  = tid & 31;
        const int i0 = (tid >> 5) << 2;
        float acc[5][4];
#pragma unroll
        for (int c = 0; c < 5; ++c) {
            float v[12];
            *(float4*)&v[0] = *(const float4*)&tmpT[c][j][i0];
            *(float4*)&v[4] = *(const float4*)&tmpT[c][j][i0 + 4];
            *(float4*)&v[8] = *(const float4*)&tmpT[c][j][i0 + 8];
            float s = ((v[0] + v[1]) + (v[2] + v[3]))
                    + ((v[4] + v[5]) + (v[6] + v[7])) + v[8];
            acc[c][0] = s;
            s += v[9]  - v[0]; acc[c][1] = s;
            s += v[10] - v[1]; acc[c][2] = s;
            s += v[11] - v[2]; acc[c][3] = s;
        }
        size_t obase = (size_t)slice * SLICE + (size_t)(th0 + i0) * 128 + (tw0 + j);
#pragma unroll
        for (int c = 0; c < 5; ++c)
#pragma unroll
            for (int k = 0; k < 4; ++k)
                buf[(size_t)c * NVOX + obase + (size_t)k * 128] =
                    (unsigned short)fmaf(acc[c][k], QSCALE, 0.5f);
    }
    __syncthreads();
}

__global__ __launch_bounds__(320, 2)
void lncc_wh_kernel(const float* __restrict__ f, const float* __restrict__ w,
                    unsigned short* __restrict__ buf) {
    // grid.x = 512 = 2 batches x 16 dgroups(8 slices) x 16 tiles
    // bijective XCD swizzle (512 % 8 == 0): contiguous 64-block chunk per XCD
    const int bid  = (blockIdx.x & 7) * 64 + (blockIdx.x >> 3);
    const int tile = bid & 15;
    const int dg   = (bid >> 4) & 15;
    const int b    = bid >> 8;
    const int th0  = (tile >> 2) << 5;
    const int tw0  = (tile & 3) << 5;
    const int d0   = dg << 3;
    const int tid  = threadIdx.x;

    __shared__ __align__(16) float tmpT[5][32][44];   // [ch][j][i]

    // per-thread fixed W-pass task geometry
    const int i      = tid >> 3;
    const int j0     = (tid & 7) << 2;
    const int rowoff = refl(th0 + i - 4) * 128;
    const int jb     = tw0 + j0 - 4;
    (void)i; (void)j0;

    const float* fb = f + (size_t)b * 128 * SLICE;
    const float* wb = w + (size_t)b * 128 * SLICE;

    float fA[12], wA[12], fB[12], wB[12];

    load_slice(fb + (size_t)d0 * SLICE, wb + (size_t)d0 * SLICE, rowoff, jb, fA, wA);
#pragma unroll
    for (int k = 0; k < 8; k += 2) {
        const int d = d0 + k;
        load_slice(fb + (size_t)(d + 1) * SLICE, wb + (size_t)(d + 1) * SLICE,
                   rowoff, jb, fB, wB);
        wh_compute_store(fA, wA, tmpT, tid, th0, tw0, b * 128 + d, buf);
        if (k + 2 < 8)
            load_slice(fb + (size_t)(d + 2) * SLICE, wb + (size_t)(d + 2) * SLICE,
                       rowoff, jb, fA, wA);
        wh_compute_store(fB, wB, tmpT, tid, th0, tw0, b * 128 + d + 1, buf);
    }
}

__global__ __launch_bounds__(256)
void lncc_d_kernel(const unsigned short* __restrict__ buf,
                   float* __restrict__ partials) {
    // 524288 threads: thread -> (b, dchunk(16), h, w), 8 d-outputs each
    const int gtid = blockIdx.x * 256 + threadIdx.x;
    const int wq = gtid & 127;
    const int h  = (gtid >> 7) & 127;
    const int dc = (gtid >> 14) & 15;
    const int b  = gtid >> 18;
    const int d0 = dc << 3;

    float s[5][8];
#pragma unroll
    for (int c = 0; c < 5; ++c) {
        const unsigned short* bc = buf + (size_t)c * NVOX
                                 + (size_t)b * (128 * SLICE)
                                 + (size_t)h * 128 + wq;
        float v[16];
#pragma unroll
        for (int t = 0; t < 16; ++t) {
            int d = refl(d0 - 4 + t);
            v[t] = (float)bc[(size_t)d * SLICE];
        }
        float acc = 0.f;
#pragma unroll
        for (int t = 0; t < 9; ++t) acc += v[t];
        s[c][0] = acc;
#pragma unroll
        for (int j = 1; j < 8; ++j) {
            acc += v[j + 8] - v[j - 1];
            s[c][j] = acc;
        }
    }

    float lsum = 0.f;
#pragma unroll
    for (int j = 0; j < 8; ++j) {
        float mf = s[0][j] * DQ;
        float mw = s[1][j] * DQ;
        float sgf = fmaxf(s[2][j] * DQ - mf * mf, 1e-8f);
        float sgw = fmaxf(s[3][j] * DQ - mw * mw, 1e-8f);
        float sfw = s[4][j] * DQ - mf * mw;
        float denom = fmaxf(sqrtf(fmaxf(sgf * sgw, 1e-16f)), 1e-8f);
        float l = sfw / denom;
        lsum += fminf(fmaxf(l, -10.f), 10.f);
    }

#pragma unroll
    for (int off = 32; off > 0; off >>= 1)
        lsum += __shfl_down(lsum, off, 64);
    __shared__ float red[4];
    int lane = threadIdx.x & 63, wid = threadIdx.x >> 6;
    if (lane == 0) red[wid] = lsum;
    __syncthreads();
    if (threadIdx.x == 0)
        partials[blockIdx.x] = red[0] + red[1] + red[2] + red[3];
}

__global__ __launch_bounds__(256)
void lncc_final_kernel(const float* __restrict__ partials, int n,
                       float* __restrict__ out) {
    __shared__ double rd[256];
    double acc = 0.0;
    for (int i = threadIdx.x; i < n; i += 256) acc += (double)partials[i];
    rd[threadIdx.x] = acc;
    __syncthreads();
    for (int s = 128; s > 0; s >>= 1) {
        if (threadIdx.x < s) rd[threadIdx.x] += rd[threadIdx.x + s];
        __syncthreads();
    }
    if (threadIdx.x == 0) out[0] = (float)(-rd[0] / (double)NVOX);
}

extern "C" void kernel_launch(void* const* d_in, const int* in_sizes, int n_in,
                              void* d_out, int out_size, void* d_ws, size_t ws_size,
                              hipStream_t stream) {
    const float* f = (const float*)d_in[0];
    const float* w = (const float*)d_in[1];
    float* out = (float*)d_out;

    unsigned short* buf = (unsigned short*)d_ws;              // 5*NVOX u16 = 40 MB
    float* partials = (float*)((char*)d_ws + (size_t)5 * NVOX * 2); // 2048 floats

    lncc_wh_kernel<<<512, 320, 0, stream>>>(f, w, buf);
    lncc_d_kernel<<<2048, 256, 0, stream>>>(buf, partials);
    lncc_final_kernel<<<1, 256, 0, stream>>>(partials, 2048, out);
}